// Round 2
// baseline (232.302 us; speedup 1.0000x reference)
//
#include <hip/hip_runtime.h>
#include <hip/hip_bf16.h>
#include <stdint.h>
#include <math.h>

#define NB 32
#define NF 512
#define NH 8
#define ND 64
#define NS 256
#define TOPK 51
#define STILE 16
#define LDSF (NF + 1)   // padded LDS row stride

__device__ __forceinline__ float wave_sum_f32(float v) {
#pragma unroll
  for (int o = 32; o > 0; o >>= 1) v += __shfl_xor(v, o, 64);
  return v;
}

// Bit-exact replication of numpy pairwise_sum for n=512, f32.
// Tree: pw(512) = (B0 + B1) + (B2 + B3); each Bk is a 128-block computed with
// 8 interleaved accumulators r[c] (c = f%8, 16 sequential adds each), combined
// as ((r0+r1)+(r2+r3)) + ((r4+r5)+(r6+r7)).
// Row resides in LDS. Every lane returns the same total (f32 add is
// commutative bitwise, so mirrored/reordered operand pairs give equal bits).
__device__ __forceinline__ float np_pairwise_sum_512(const float* __restrict__ row, int lane) {
  const int c2 = lane & 31;          // 32 chains; upper half mirrors lower
  const int k  = c2 >> 3;            // 128-block index 0..3
  const int c  = c2 & 7;             // accumulator index 0..7
  const float* blk = row + 128 * k;
  float r = blk[c];
#pragma unroll
  for (int m = 1; m < 16; ++m) r += blk[c + 8 * m];   // exact sequential order
  float s = r + __shfl_xor(r, 1, 64);
  s = s + __shfl_xor(s, 2, 64);
  s = s + __shfl_xor(s, 4, 64);      // every lane of block k now holds Bk
  float u = s + __shfl_xor(s, 8, 64);
  u = u + __shfl_xor(u, 16, 64);     // (B0+B1)+(B2+B3) in every lane
  return u;
}

__global__ __launch_bounds__(1024, 1)
void gating_attention_kernel(const float* __restrict__ vals,   // [B,F,H,D]
                             const float* __restrict__ dlg,    // [B,F,H,S]
                             const float* __restrict__ alpha,  // [H,S,F]
                             const float* __restrict__ betap,  // [H,S,1]
                             float* __restrict__ out)          // [B,S,H,D]
{
#pragma clang fp contract(off)       // numpy does mul THEN add; forbid fma fusion
  __shared__ float dl_t[STILE * LDSF];
  __shared__ uint2 pairs[STILE][64];

  const int bh   = blockIdx.x;
  const int b    = bh >> 3;
  const int h    = bh & 7;
  const int tid  = threadIdx.x;
  const int w    = tid >> 6;
  const int lane = tid & 63;
  const unsigned long long lmask = (1ull << lane) - 1ull;
  const float scalef = (float)0.04419417382415922;   // f32(1/sqrt(512))

  for (int t = 0; t < NS / STILE; ++t) {
    const int s0 = t * STILE;

    // ---- stage data_logits tile, transposed, coalesced float4 reads ----
#pragma unroll
    for (int cc = 0; cc < 2; ++cc) {
      int i  = cc * 1024 + tid;
      int f  = i >> 2;
      int sg = (i & 3) << 2;
      const float4 v4 = *reinterpret_cast<const float4*>(
          dlg + ((((size_t)b * NF + f) * NH + h) * NS + (size_t)(s0 + sg)));
      dl_t[(sg + 0) * LDSF + f] = v4.x;
      dl_t[(sg + 1) * LDSF + f] = v4.y;
      dl_t[(sg + 2) * LDSF + f] = v4.z;
      dl_t[(sg + 3) * LDSF + f] = v4.w;
    }
    __syncthreads();

    const int s = s0 + w;
    float* row = dl_t + w * LDSF;    // this wave's private row

    float a[8], x[8];
#pragma unroll
    for (int j = 0; j < 8; ++j)
      a[j] = alpha[((size_t)h * NS + s) * NF + lane + 64 * j];
#pragma unroll
    for (int j = 0; j < 8; ++j)
      x[j] = row[lane + 64 * j];

    // ---- mu: numpy-exact pairwise sum / 512 (exact pow2 scale) ----
    const float S1 = np_pairwise_sum_512(row, lane);
    const float mu = S1 * (1.0f / 512.0f);

    // ---- var: numpy computes t=(x-mu); t*t; pairwise sum / 512 ----
    float tv[8];
#pragma unroll
    for (int j = 0; j < 8; ++j) {
      tv[j] = x[j] - mu;
      row[lane + 64 * j] = tv[j] * tv[j];   // overwrite row with squares
    }
    const float S2  = np_pairwise_sum_512(row, lane);
    const float var = S2 * (1.0f / 512.0f);
    const float stdv = (float)sqrt((double)(var + 1e-6f)) + 1e-6f;

    // ---- beta = softplus(bp) with f32 intermediate like numpy ----
    const float bp = betap[h * NS + s];
    const float eb = (float)exp((double)bp);          // f32(exp(bp))
    const float beta = (float)log1p((double)eb);      // f32(log1p(f32 exp))

    // ---- logits: exact numpy f32 op order, no contraction ----
    float lg[8];
    unsigned key[8];
#pragma unroll
    for (int j = 0; j < 8; ++j) {
      float z  = tv[j] / stdv;       // IEEE f32 divide
      float m  = beta * z;
      float af = a[j] * scalef;
      float l  = af + m;
      lg[j] = l;
      unsigned bits = __float_as_uint(l);
      key[j] = (bits & 0x80000000u) ? ~bits : (bits | 0x80000000u);
    }

    // ---- exact top-k threshold on u32 keys, bisection + early exit ----
    unsigned lo = 0u, hi = 0xFFFFFFFFu;
    while (lo < hi) {
      unsigned mid = hi - ((hi - lo) >> 1);
      int c = 0;
#pragma unroll
      for (int j = 0; j < 8; ++j) c += __popcll(__ballot(key[j] >= mid));
      if (c >= TOPK) { lo = mid; if (c == TOPK) break; }
      else hi = mid - 1;
    }
    const unsigned T = lo;

    // ---- tie handling: keep all >T, fill remaining with ==T by lowest f ----
    int g = 0;
#pragma unroll
    for (int j = 0; j < 8; ++j) g += __popcll(__ballot(key[j] > T));
    const int need = TOPK - g;

    bool keep[8];
    int cumt = 0;
#pragma unroll
    for (int j = 0; j < 8; ++j) {
      unsigned long long meq = __ballot(key[j] == T);
      int tr = cumt + __popcll(meq & lmask);
      cumt += __popcll(meq);
      keep[j] = (key[j] > T) || ((key[j] == T) && (tr < need));
    }

    // threshold back to float for exp offset
    unsigned tb = (T & 0x80000000u) ? (T ^ 0x80000000u) : ~T;
    const float thrf = __uint_as_float(tb);

    // ---- softmax numerators over kept set ----
    float p[8];
    float zs = 0.0f;
#pragma unroll
    for (int j = 0; j < 8; ++j) {
      float e = keep[j] ? expf(lg[j] - thrf) : 0.0f;
      p[j] = e;
      zs += e;
    }
    zs = wave_sum_f32(zs);
    const float rz = 1.0f / zs;

    // ---- compact kept (f, p) pairs into LDS ----
    pairs[w][lane] = make_uint2(0u, 0u);
    int base = 0;
#pragma unroll
    for (int j = 0; j < 8; ++j) {
      unsigned long long mk = __ballot(keep[j]);
      int idx = base + __popcll(mk & lmask);
      if (keep[j] && idx < 64)
        pairs[w][idx] = make_uint2((unsigned)(lane + 64 * j), __float_as_uint(p[j]));
      base += __popcll(mk);
    }
    base = __builtin_amdgcn_readfirstlane(base);   // == 51
    int nk = (base + 3) & ~3;
    if (nk > 64) nk = 64;

    // ---- sparse PV gather: 4 loads in flight ----
    const float* vb = vals + (((size_t)b * NF) * NH + h) * ND + lane;
    float acc = 0.0f;
    for (int k0 = 0; k0 < nk; k0 += 4) {
      uint2 e0 = pairs[w][k0 + 0];
      uint2 e1 = pairs[w][k0 + 1];
      uint2 e2 = pairs[w][k0 + 2];
      uint2 e3 = pairs[w][k0 + 3];
      float v0 = vb[e0.x * (NH * ND)];
      float v1 = vb[e1.x * (NH * ND)];
      float v2 = vb[e2.x * (NH * ND)];
      float v3 = vb[e3.x * (NH * ND)];
      acc = fmaf(__uint_as_float(e0.y), v0, acc);
      acc = fmaf(__uint_as_float(e1.y), v1, acc);
      acc = fmaf(__uint_as_float(e2.y), v2, acc);
      acc = fmaf(__uint_as_float(e3.y), v3, acc);
    }

    out[(((size_t)b * NS + s) * NH + h) * ND + lane] = acc * rz;

    __syncthreads();
  }
}

extern "C" void kernel_launch(void* const* d_in, const int* in_sizes, int n_in,
                              void* d_out, int out_size, void* d_ws, size_t ws_size,
                              hipStream_t stream) {
  const float* vals  = (const float*)d_in[0];
  const float* dlg   = (const float*)d_in[1];
  const float* alpha = (const float*)d_in[2];
  const float* betap = (const float*)d_in[3];
  float* out = (float*)d_out;

  dim3 grid(NB * NH);
  dim3 block(1024);
  gating_attention_kernel<<<grid, block, 0, stream>>>(vals, dlg, alpha, betap, out);
}

// Round 3
// 129.622 us; speedup vs baseline: 1.7921x; 1.7921x over previous
//
#include <hip/hip_runtime.h>
#include <hip/hip_bf16.h>
#include <stdint.h>
#include <math.h>

#define NB 32
#define NF 512
#define NH 8
#define ND 64
#define NS 256
#define TOPK 51
#define STILE 16
#define LDSF (NF + 1)   // padded LDS row stride

__device__ __forceinline__ float wave_sum_f32(float v) {
#pragma unroll
  for (int o = 32; o > 0; o >>= 1) v += __shfl_xor(v, o, 64);
  return v;
}

// Bit-exact replication of numpy pairwise_sum for n=512, f32.
// pw(512) = (B0 + B1) + (B2 + B3); each Bk a 128-block with 8 interleaved
// accumulators combined ((r0+r1)+(r2+r3)) + ((r4+r5)+(r6+r7)).
__device__ __forceinline__ float np_pairwise_sum_512(const float* __restrict__ row, int lane) {
  const int c2 = lane & 31;
  const int k  = c2 >> 3;
  const int c  = c2 & 7;
  const float* blk = row + 128 * k;
  float r = blk[c];
#pragma unroll
  for (int m = 1; m < 16; ++m) r += blk[c + 8 * m];   // exact sequential order
  float s = r + __shfl_xor(r, 1, 64);
  s = s + __shfl_xor(s, 2, 64);
  s = s + __shfl_xor(s, 4, 64);
  float u = s + __shfl_xor(s, 8, 64);
  u = u + __shfl_xor(u, 16, 64);
  return u;
}

__global__ __launch_bounds__(1024, 8)   // cap VGPR at 64 -> 2 blocks/CU resident
void gating_attention_kernel(const float* __restrict__ vals,   // [B,F,H,D]
                             const float* __restrict__ dlg,    // [B,F,H,S]
                             const float* __restrict__ alpha,  // [H,S,F]
                             const float* __restrict__ betap,  // [H,S,1]
                             float* __restrict__ out)          // [B,S,H,D]
{
#pragma clang fp contract(off)       // numpy does mul THEN add; forbid fma fusion
  __shared__ float dl_t[STILE * LDSF];
  __shared__ uint2 pairs[STILE][64];

  const int blk  = blockIdx.x;       // grid = 256 * 16: [bh][tile]
  const int bh   = blk >> 4;
  const int t    = blk & 15;
  const int b    = bh >> 3;
  const int h    = bh & 7;
  const int s0   = t * STILE;
  const int tid  = threadIdx.x;
  const int w    = tid >> 6;
  const int lane = tid & 63;
  const unsigned long long lmask = (1ull << lane) - 1ull;
  const float scalef = (float)0.04419417382415922;   // f32(1/sqrt(512))

  // ---- stage data_logits tile, transposed, coalesced float4 reads ----
#pragma unroll
  for (int cc = 0; cc < 2; ++cc) {
    int i  = cc * 1024 + tid;
    int f  = i >> 2;
    int sg = (i & 3) << 2;
    const float4 v4 = *reinterpret_cast<const float4*>(
        dlg + ((((size_t)b * NF + f) * NH + h) * NS + (size_t)(s0 + sg)));
    dl_t[(sg + 0) * LDSF + f] = v4.x;
    dl_t[(sg + 1) * LDSF + f] = v4.y;
    dl_t[(sg + 2) * LDSF + f] = v4.z;
    dl_t[(sg + 3) * LDSF + f] = v4.w;
  }
  __syncthreads();

  const int s = s0 + w;
  float* row = dl_t + w * LDSF;      // this wave's private row

  float a[8], x[8];
#pragma unroll
  for (int j = 0; j < 8; ++j)
    a[j] = alpha[((size_t)h * NS + s) * NF + lane + 64 * j];
#pragma unroll
  for (int j = 0; j < 8; ++j)
    x[j] = row[lane + 64 * j];

  // ---- mu: numpy-exact pairwise sum / 512 ----
  const float S1 = np_pairwise_sum_512(row, lane);
  const float mu = S1 * (1.0f / 512.0f);

  // ---- var: t=(x-mu); t*t; pairwise sum / 512 ----
  float tv[8];
#pragma unroll
  for (int j = 0; j < 8; ++j) {
    tv[j] = x[j] - mu;
    row[lane + 64 * j] = tv[j] * tv[j];
  }
  const float S2  = np_pairwise_sum_512(row, lane);
  const float var = S2 * (1.0f / 512.0f);
  const float stdv = (float)sqrt((double)(var + 1e-6f)) + 1e-6f;

  // ---- beta = softplus(bp), f32 intermediates ----
  const float bp = betap[h * NS + s];
  const float eb = (float)exp((double)bp);
  const float beta = (float)log1p((double)eb);

  // ---- logits: exact numpy f32 op order, no contraction ----
  float lg[8];
  unsigned key[8];
#pragma unroll
  for (int j = 0; j < 8; ++j) {
    float z  = tv[j] / stdv;         // IEEE f32 divide (ordering-critical)
    float m  = beta * z;
    float af = a[j] * scalef;
    float l  = af + m;
    lg[j] = l;
    unsigned bits = __float_as_uint(l);
    key[j] = (bits & 0x80000000u) ? ~bits : (bits | 0x80000000u);
  }

  // ---- tight initial bounds from wave min/max of keys ----
  unsigned kmax = key[0], kmin = key[0];
#pragma unroll
  for (int j = 1; j < 8; ++j) {
    kmax = key[j] > kmax ? key[j] : kmax;
    kmin = key[j] < kmin ? key[j] : kmin;
  }
#pragma unroll
  for (int o = 32; o > 0; o >>= 1) {
    unsigned om = (unsigned)__shfl_xor((int)kmax, o, 64);
    unsigned on = (unsigned)__shfl_xor((int)kmin, o, 64);
    kmax = om > kmax ? om : kmax;
    kmin = on < kmin ? on : kmin;
  }

  // ---- exact top-k threshold: bisection, early exit ----
  unsigned lo = kmin, hi = kmax;
  int cnt = NF;                      // count(key >= lo)
  while (lo < hi) {
    unsigned mid = hi - ((hi - lo) >> 1);
    int cm = 0;
#pragma unroll
    for (int j = 0; j < 8; ++j) cm += __popcll(__ballot(key[j] >= mid));
    if (cm >= TOPK) { lo = mid; cnt = cm; if (cm == TOPK) break; }
    else hi = mid - 1;
  }
  const unsigned T = lo;
  const bool exact = (cnt == TOPK);  // wave-uniform

  // ---- keep mask; tie resolution only when needed ----
  bool keep[8];
  if (exact) {
#pragma unroll
    for (int j = 0; j < 8; ++j) keep[j] = (key[j] >= T);
  } else {
    int g = 0;
#pragma unroll
    for (int j = 0; j < 8; ++j) g += __popcll(__ballot(key[j] > T));
    const int need = TOPK - g;
    int cumt = 0;
#pragma unroll
    for (int j = 0; j < 8; ++j) {
      unsigned long long meq = __ballot(key[j] == T);
      int tr = cumt + __popcll(meq & lmask);
      cumt += __popcll(meq);
      keep[j] = (key[j] > T) || ((key[j] == T) && (tr < need));
    }
  }

  // threshold value back to float for exp offset
  unsigned tb = (T & 0x80000000u) ? (T ^ 0x80000000u) : ~T;
  const float thrf = __uint_as_float(tb);

  // ---- softmax numerators over kept set ----
  float p[8];
  float zs = 0.0f;
#pragma unroll
  for (int j = 0; j < 8; ++j) {
    float e = keep[j] ? __expf(lg[j] - thrf) : 0.0f;
    p[j] = e;
    zs += e;
  }
  zs = wave_sum_f32(zs);
  const float rz = 1.0f / zs;

  // ---- compact kept (f, p) pairs into LDS (exactly TOPK entries) ----
  int base = 0;
#pragma unroll
  for (int j = 0; j < 8; ++j) {
    unsigned long long mk = __ballot(keep[j]);
    int idx = base + __popcll(mk & lmask);
    if (keep[j]) pairs[w][idx] = make_uint2((unsigned)(lane + 64 * j), __float_as_uint(p[j]));
    base += __popcll(mk);
  }
  const int nk = (TOPK + 3) & ~3;    // 52
  if (lane >= TOPK && lane < nk) pairs[w][lane] = make_uint2(0u, 0u);  // pad slot

  // ---- sparse PV gather: 4 independent accumulators ----
  const float* vb = vals + (((size_t)b * NF) * NH + h) * ND + lane;
  float acc0 = 0.0f, acc1 = 0.0f, acc2 = 0.0f, acc3 = 0.0f;
  for (int k0 = 0; k0 < nk; k0 += 4) {
    uint2 e0 = pairs[w][k0 + 0];
    uint2 e1 = pairs[w][k0 + 1];
    uint2 e2 = pairs[w][k0 + 2];
    uint2 e3 = pairs[w][k0 + 3];
    float v0 = vb[e0.x * (NH * ND)];
    float v1 = vb[e1.x * (NH * ND)];
    float v2 = vb[e2.x * (NH * ND)];
    float v3 = vb[e3.x * (NH * ND)];
    acc0 = fmaf(__uint_as_float(e0.y), v0, acc0);
    acc1 = fmaf(__uint_as_float(e1.y), v1, acc1);
    acc2 = fmaf(__uint_as_float(e2.y), v2, acc2);
    acc3 = fmaf(__uint_as_float(e3.y), v3, acc3);
  }
  const float acc = (acc0 + acc1) + (acc2 + acc3);

  out[(((size_t)b * NS + s) * NH + h) * ND + lane] = acc * rz;
}

extern "C" void kernel_launch(void* const* d_in, const int* in_sizes, int n_in,
                              void* d_out, int out_size, void* d_ws, size_t ws_size,
                              hipStream_t stream) {
  const float* vals  = (const float*)d_in[0];
  const float* dlg   = (const float*)d_in[1];
  const float* alpha = (const float*)d_in[2];
  const float* betap = (const float*)d_in[3];
  float* out = (float*)d_out;

  dim3 grid(NB * NH * (NS / STILE));   // 4096 blocks: one per (b,h,s-tile)
  dim3 block(1024);
  gating_attention_kernel<<<grid, block, 0, stream>>>(vals, dlg, alpha, betap, out);
}

// Round 4
// 117.663 us; speedup vs baseline: 1.9743x; 1.1016x over previous
//
#include <hip/hip_runtime.h>
#include <hip/hip_bf16.h>
#include <stdint.h>
#include <math.h>

#define NB 32
#define NF 512
#define NH 8
#define ND 64
#define NS 256
#define TOPK 51
#define STILE 16
#define LDSF 537   // swizzled row stride; OFF(f)=f+8*(f>>7) max 535; 537%32=25 spreads staging rows

__device__ __forceinline__ float wave_sum_f32(float v) {
#pragma unroll
  for (int o = 32; o > 0; o >>= 1) v += __shfl_xor(v, o, 64);
  return v;
}

// prefix popcount of mask below this lane (v_mbcnt pair)
__device__ __forceinline__ int lane_prefix(unsigned long long m) {
  return __builtin_amdgcn_mbcnt_hi((unsigned)(m >> 32),
         __builtin_amdgcn_mbcnt_lo((unsigned)m, 0u));
}

// Bit-exact numpy pairwise_sum(n=512) on a swizzled LDS row.
// Row element f lives at word OFF(f)=f+8*(f>>7); block k is contiguous at 136k.
// Chain (k,c): 16 sequential adds; banks (8k+c+8m)%32 cover all 32 -> conflict-free.
__device__ __forceinline__ float np_pairwise_sum_512(const float* __restrict__ row, int lane) {
  const int c2 = lane & 31;
  const int k  = c2 >> 3;
  const int c  = c2 & 7;
  const float* blk = row + 136 * k;
  float r = blk[c];
#pragma unroll
  for (int m = 1; m < 16; ++m) r += blk[c + 8 * m];   // exact sequential order
  float s = r + __shfl_xor(r, 1, 64);
  s = s + __shfl_xor(s, 2, 64);
  s = s + __shfl_xor(s, 4, 64);
  float u = s + __shfl_xor(s, 8, 64);
  u = u + __shfl_xor(u, 16, 64);
  return u;
}

__global__ void beta_kernel(const float* __restrict__ bp, float* __restrict__ bf) {
  int i = blockIdx.x * 1024 + threadIdx.x;
  if (i < NH * NS) {
    double e = exp((double)bp[i]);         // f32 intermediate semantics preserved:
    bf[i] = (float)log1p(e);               // numpy softplus on f32 input, f32 result
  }
}

__global__ __launch_bounds__(1024, 8)   // keep VGPR<=64 -> 2 blocks (32 waves)/CU
void gating_attention_kernel(const float* __restrict__ vals,   // [B,F,H,D]
                             const float* __restrict__ dlg,    // [B,F,H,S]
                             const float* __restrict__ alpha,  // [H,S,F]
                             const float* __restrict__ betap,  // [H,S,1]
                             const float* __restrict__ betaf,  // [H*S] precomputed softplus (or null)
                             float* __restrict__ out)          // [B,S,H,D]
{
#pragma clang fp contract(off)       // numpy does mul THEN add; forbid fma fusion
  __shared__ float dl_t[STILE * LDSF];
  __shared__ uint2 pairs[STILE][64];

  const int blk  = blockIdx.x;       // swizzled: bh = blk&255 -> XCD = h for L2 locality
  const int bh   = blk & 255;
  const int t    = blk >> 8;
  const int b    = bh >> 3;
  const int h    = bh & 7;
  const int s0   = t * STILE;
  const int tid  = threadIdx.x;
  const int w    = tid >> 6;
  const int lane = tid & 63;
  const float scalef = (float)0.04419417382415922;   // f32(1/sqrt(512))

  // ---- stage data_logits tile, transposed, swizzled columns ----
#pragma unroll
  for (int cc = 0; cc < 2; ++cc) {
    int i  = cc * 1024 + tid;
    int f  = i >> 2;
    int sg = (i & 3) << 2;
    int fo = f + ((f >> 7) << 3);
    const float4 v4 = *reinterpret_cast<const float4*>(
        dlg + ((((size_t)b * NF + f) * NH + h) * NS + (size_t)(s0 + sg)));
    dl_t[(sg + 0) * LDSF + fo] = v4.x;
    dl_t[(sg + 1) * LDSF + fo] = v4.y;
    dl_t[(sg + 2) * LDSF + fo] = v4.z;
    dl_t[(sg + 3) * LDSF + fo] = v4.w;
  }
  __syncthreads();

  const int s = s0 + w;
  float* row = dl_t + w * LDSF;      // this wave's private swizzled row

  float a[8], x[8];
#pragma unroll
  for (int j = 0; j < 8; ++j)
    a[j] = alpha[((size_t)h * NS + s) * NF + lane + 64 * j];
#pragma unroll
  for (int j = 0; j < 8; ++j)
    x[j] = row[lane + 64 * j + 8 * (j >> 1)];   // OFF(lane+64j), compile-time per j

  // ---- mu: numpy-exact pairwise sum / 512 ----
  const float S1 = np_pairwise_sum_512(row, lane);
  const float mu = S1 * (1.0f / 512.0f);

  // ---- var: t=(x-mu); t*t; pairwise sum / 512 ----
  float tv[8];
#pragma unroll
  for (int j = 0; j < 8; ++j) {
    tv[j] = x[j] - mu;
    row[lane + 64 * j + 8 * (j >> 1)] = tv[j] * tv[j];
  }
  const float S2  = np_pairwise_sum_512(row, lane);
  const float var = S2 * (1.0f / 512.0f);
  const float stdv = sqrtf(var + 1e-6f) + 1e-6f;   // IEEE-correct f32 sqrt (numpy op)

  // ---- beta = softplus(bp): table lookup (or inline f64 fallback) ----
  float beta;
  if (betaf) beta = betaf[h * NS + s];
  else {
    double e = exp((double)betap[h * NS + s]);
    beta = (float)log1p(e);
  }

  // ---- logits: numpy f32 op order; divide via uniform f64 reciprocal ----
  const double rd = 1.0 / (double)stdv;   // one f64 div per wave
  float lg[8];
  unsigned key[8];
#pragma unroll
  for (int j = 0; j < 8; ++j) {
    float z  = (float)((double)tv[j] * rd);   // == IEEE f32 div up to 2^-29 corner
    float m  = beta * z;
    float af = a[j] * scalef;
    float l  = af + m;
    lg[j] = l;
    unsigned bits = __float_as_uint(l);
    key[j] = (bits & 0x80000000u) ? ~bits : (bits | 0x80000000u);
  }

  // ---- tight initial bounds from wave min/max of keys ----
  unsigned kmax = key[0], kmin = key[0];
#pragma unroll
  for (int j = 1; j < 8; ++j) {
    kmax = key[j] > kmax ? key[j] : kmax;
    kmin = key[j] < kmin ? key[j] : kmin;
  }
#pragma unroll
  for (int o = 32; o > 0; o >>= 1) {
    unsigned om = (unsigned)__shfl_xor((int)kmax, o, 64);
    unsigned on = (unsigned)__shfl_xor((int)kmin, o, 64);
    kmax = om > kmax ? om : kmax;
    kmin = on < kmin ? on : kmin;
  }

  // ---- exact top-k threshold: bisection, early exit ----
  unsigned lo = kmin, hi = kmax;
  int cnt = NF;
  while (lo < hi) {
    unsigned mid = hi - ((hi - lo) >> 1);
    int cm = 0;
#pragma unroll
    for (int j = 0; j < 8; ++j) cm += __popcll(__ballot(key[j] >= mid));
    if (cm >= TOPK) { lo = mid; cnt = cm; if (cm == TOPK) break; }
    else hi = mid - 1;
  }
  const unsigned T = lo;
  const bool exact = (cnt == TOPK);

  // ---- keep mask; tie resolution only when needed ----
  bool keep[8];
  if (exact) {
#pragma unroll
    for (int j = 0; j < 8; ++j) keep[j] = (key[j] >= T);
  } else {
    int g = 0;
#pragma unroll
    for (int j = 0; j < 8; ++j) g += __popcll(__ballot(key[j] > T));
    const int need = TOPK - g;
    int cumt = 0;
#pragma unroll
    for (int j = 0; j < 8; ++j) {
      unsigned long long meq = __ballot(key[j] == T);
      int tr = cumt + lane_prefix(meq);
      cumt += __popcll(meq);
      keep[j] = (key[j] > T) || ((key[j] == T) && (tr < need));
    }
  }

  // threshold value back to float for exp offset
  unsigned tb = (T & 0x80000000u) ? (T ^ 0x80000000u) : ~T;
  const float thrf = __uint_as_float(tb);

  // ---- softmax numerators over kept set ----
  float p[8];
  float zs = 0.0f;
#pragma unroll
  for (int j = 0; j < 8; ++j) {
    float e = keep[j] ? __expf(lg[j] - thrf) : 0.0f;
    p[j] = e;
    zs += e;
  }
  zs = wave_sum_f32(zs);
  const float rz = 1.0f / zs;

  // ---- compact kept (scaled f-offset, p) pairs into LDS ----
  int base = 0;
#pragma unroll
  for (int j = 0; j < 8; ++j) {
    unsigned long long mk = __ballot(keep[j]);
    int idx = base + lane_prefix(mk);
    if (keep[j])
      pairs[w][idx] = make_uint2((unsigned)((lane + 64 * j) << 9),  // f*NH*ND element offset
                                 __float_as_uint(p[j]));
    base += __popcll(mk);
  }
  const int nk = (TOPK + 3) & ~3;    // 52
  if (lane >= TOPK && lane < nk) pairs[w][lane] = make_uint2(0u, 0u);  // pad slot

  // ---- sparse PV gather: 4 independent accumulators, pre-scaled offsets ----
  const float* vb = vals + (((size_t)b * NF) * NH + h) * ND + lane;
  float acc0 = 0.0f, acc1 = 0.0f, acc2 = 0.0f, acc3 = 0.0f;
  for (int k0 = 0; k0 < nk; k0 += 4) {
    uint2 e0 = pairs[w][k0 + 0];
    uint2 e1 = pairs[w][k0 + 1];
    uint2 e2 = pairs[w][k0 + 2];
    uint2 e3 = pairs[w][k0 + 3];
    float v0 = vb[e0.x];
    float v1 = vb[e1.x];
    float v2 = vb[e2.x];
    float v3 = vb[e3.x];
    acc0 = fmaf(__uint_as_float(e0.y), v0, acc0);
    acc1 = fmaf(__uint_as_float(e1.y), v1, acc1);
    acc2 = fmaf(__uint_as_float(e2.y), v2, acc2);
    acc3 = fmaf(__uint_as_float(e3.y), v3, acc3);
  }
  const float acc = (acc0 + acc1) + (acc2 + acc3);

  out[(((size_t)b * NS + s) * NH + h) * ND + lane] = acc * rz;
}

extern "C" void kernel_launch(void* const* d_in, const int* in_sizes, int n_in,
                              void* d_out, int out_size, void* d_ws, size_t ws_size,
                              hipStream_t stream) {
  const float* vals  = (const float*)d_in[0];
  const float* dlg   = (const float*)d_in[1];
  const float* alpha = (const float*)d_in[2];
  const float* betap = (const float*)d_in[3];
  float* out = (float*)d_out;

  float* betaf = nullptr;
  if (ws_size >= (size_t)(NH * NS) * sizeof(float)) {
    betaf = (float*)d_ws;
    beta_kernel<<<2, 1024, 0, stream>>>(betap, betaf);
  }

  dim3 grid(NB * NH * (NS / STILE));   // 4096 blocks
  dim3 block(1024);
  gating_attention_kernel<<<grid, block, 0, stream>>>(vals, dlg, alpha, betap, betaf, out);
}